// Round 1
// baseline (6483.725 us; speedup 1.0000x reference)
//
#include <hip/hip_runtime.h>

// DynamicRNNEncoder on MI355X.
// Strategy: cooperative persistent kernel, weights register-resident (f16),
// one hand-rolled grid barrier per timestep. Dynamic-token cache handled via
// precomputed "previous occurrence" indices + per-step state history.

typedef _Float16 f16;
typedef _Float16 f16x8 __attribute__((ext_vector_type(8)));
typedef float f32x4 __attribute__((ext_vector_type(4)));

#define B_ 64
#define T_ 256
#define H_ 512
#define EN_ 256
#define ET_ 256
#define D_ 256
#define VN_ 300
#define VS_ 100

#define NB_MAIN_ 128   // 4 main units (16 gate rows) each
#define NB_DYN_ 64     // 4 dyn units each
#define NBLK_ 192
#define NTHR_ 256

// ---- workspace layout (bytes, all 1024-aligned) ----
static constexpr size_t OFF_CNT  = 0;                                   // barrier counter
static constexpr size_t OFF_EMBN = 1024;                                // embN f16  [300][256]
static constexpr size_t OFF_EMBT = OFF_EMBN + (size_t)VN_ * EN_ * 2;    // embT f16  [100][256]
static constexpr size_t OFF_DINH = OFF_EMBT + (size_t)VS_ * ET_ * 2;    // dyn_init_h f16 [256]
static constexpr size_t OFF_PREV = OFF_DINH + 1024;                     // prev int32 [T][B]
static constexpr size_t OFF_HH   = OFF_PREV + (size_t)T_ * B_ * 4;      // Hhist f16 [T+1][B][H]
static constexpr size_t OFF_HD   = OFF_HH + (size_t)(T_ + 1) * B_ * H_ * 2; // HdHist f16 [T][B][D]
static constexpr size_t OFF_CD   = OFF_HD + (size_t)T_ * B_ * D_ * 2;   // CdHist f32 [T][B][D]
static constexpr size_t WS_NEED  = OFF_CD + (size_t)T_ * B_ * D_ * 4;   // ~42.3 MB

struct RnnParams {
  const int* n_input; const int* t_input; const int* s2d;
  const float* W_ih; const float* W_hh; const float* b_ih; const float* b_hh;
  const float* Wd_ih; const float* Wd_hh; const float* bd_ih; const float* bd_hh;
  const float* cell_init; const float* dyn_init_c;
  const f16* embN16; const f16* embT16; const f16* dynih16;
  const int* prev;
  f16* Hhist; f16* HdHist; float* CdHist;
  float* out; unsigned* cnt;
};

__device__ __forceinline__ float sigm(float x) { return 1.f / (1.f + __expf(-x)); }
__device__ __forceinline__ float tanh_fast(float x) {
  float e = __expf(2.f * x);
  return 1.f - 2.f / (e + 1.f);   // -> -1 / +1 at extremes, no NaN
}

// Monotonic-counter grid barrier (cooperative launch guarantees residency).
__device__ __forceinline__ void grid_barrier(unsigned* cnt, unsigned target) {
  __syncthreads();                 // waits vmcnt(0): all block stores committed
  if (threadIdx.x == 0) {
    __threadfence();               // agent-scope release (L2 writeback on gfx950)
    __hip_atomic_fetch_add(cnt, 1u, __ATOMIC_RELEASE, __HIP_MEMORY_SCOPE_AGENT);
    while (__hip_atomic_load(cnt, __ATOMIC_ACQUIRE, __HIP_MEMORY_SCOPE_AGENT) < target) {
      __builtin_amdgcn_s_sleep(2);
    }
    __threadfence();               // agent-scope acquire (cache invalidate)
  }
  __syncthreads();
}

// ---- setup: f16 conversions, Hhist[0] init, barrier counter reset ----
__global__ void setup_kernel(const float* embN, const float* embT,
                             const float* hid_init, const float* dyn_init_h,
                             f16* embN16, f16* embT16, f16* dynih16,
                             f16* Hhist0, unsigned* cnt) {
  int i = blockIdx.x * blockDim.x + threadIdx.x;
  if (i == 0) *cnt = 0u;
  if (i < VN_ * EN_) embN16[i] = (f16)embN[i];
  if (i < VS_ * ET_) embT16[i] = (f16)embT[i];
  if (i < D_)        dynih16[i] = (f16)dyn_init_h[i];
  if (i < B_ * H_)   Hhist0[i] = (f16)hid_init[i & (H_ - 1)];
}

// ---- prev-occurrence table: prev[t][b] = last t'<t with same (dynamic) token ----
__global__ void prev_kernel(const int* t_input, const int* s2d, int* prev) {
  int idx = blockIdx.x * blockDim.x + threadIdx.x;
  if (idx >= B_ * T_) return;
  int b = idx / T_, t = idx % T_;
  int tt = t_input[b * T_ + t];
  int p = -1;
  if (s2d[tt] != tt) {                     // dynamic token (static iff s2d[tt]==tt)
    for (int q = t - 1; q >= 0; --q)
      if (t_input[b * T_ + q] == tt) { p = q; break; }
  }
  prev[t * B_ + b] = p;
}

// ---- main cooperative recurrent kernel ----
__global__ __launch_bounds__(NTHR_, 1) void rnn_main(RnnParams p) {
  const int blk  = blockIdx.x;
  const int tid  = threadIdx.x;
  const int wave = tid >> 6;
  const int lane = tid & 63;
  const bool isDyn = (blk >= NB_MAIN_);
  const int u0 = isDyn ? (blk - NB_MAIN_) * 4 : blk * 4;

  __shared__ float s_bias[16];
  __shared__ float s_scr[64][17];          // acc scratch [batch][gate-n], padded
  __shared__ float s_c[64][4];             // main LSTM cell state
  __shared__ const f16*  s_aN[64];         // embN row ptr per batch
  __shared__ const f16*  s_aX[64];         // h_tensor (main) / hd_prev (dyn) ptr
  __shared__ const float* s_aC[64];        // cd_prev ptr (dyn)
  __shared__ int s_dynw[64];               // write mask (dyn rows)

  // ---- one-time: gather this block's weights into registers, fragment order ----
  // lane l supplies B-frag elems: B[k = s*32 + (l>>4)*8 + j][n = l&15]
  const int nIdx = lane & 15;
  const int ui = nIdx & 3, gate = nIdx >> 2;
  const int ko = (lane >> 4) * 8;
  f16x8 w[32];
  if (!isDyn) {
    const int r = gate * H_ + u0 + ui;     // W row: gate-major (i,f,g,o)
#pragma unroll
    for (int s = 0; s < 32; ++s) {
      const int k = s * 32 + ko;           // K: [0,256)=embN [256,512)=h_tensor [512,1024)=h
      const float* src = (k < 512) ? (p.W_ih + (size_t)r * 512 + k)
                                   : (p.W_hh + (size_t)r * 512 + (k - 512));
      f16x8 v;
#pragma unroll
      for (int j = 0; j < 8; ++j) v[j] = (f16)src[j];
      w[s] = v;
    }
  } else {
    const int r = gate * D_ + u0 + ui;
#pragma unroll
    for (int s = 0; s < 32; ++s) {
      const int k = s * 32 + ko;           // K: [0,256)=embN [256,768)=h [768,1024)=hd_prev
      const float* src = (k < 768) ? (p.Wd_ih + (size_t)r * 768 + k)
                                   : (p.Wd_hh + (size_t)r * 256 + (k - 768));
      f16x8 v;
#pragma unroll
      for (int j = 0; j < 8; ++j) v[j] = (f16)src[j];
      w[s] = v;
    }
  }
  if (tid < 16) {
    int g2 = tid >> 2, un2 = tid & 3;
    s_bias[tid] = isDyn ? (p.bd_ih[g2 * D_ + u0 + un2] + p.bd_hh[g2 * D_ + u0 + un2])
                        : (p.b_ih[g2 * H_ + u0 + un2] + p.b_hh[g2 * H_ + u0 + un2]);
  }
  { int b = tid >> 2, un = tid & 3; s_c[b][un] = isDyn ? 0.f : p.cell_init[u0 + un]; }

  unsigned target = NBLK_;
  for (int t = 0; t < T_; ++t) {
    // per-batch source pointers for this step
    if (tid < B_) {
      const int b = tid;
      const int nt = p.n_input[b * T_ + t];
      s_aN[b] = p.embN16 + (size_t)nt * EN_;
      const int tt = p.t_input[b * T_ + t];
      const int pv = p.prev[t * B_ + b];
      const f16* hd = (pv >= 0) ? (p.HdHist + ((size_t)pv * B_ + b) * D_) : p.dynih16;
      const int s2 = p.s2d[tt];
      const bool st = (s2 == tt);
      if (!isDyn) {
        s_aX[b] = st ? (p.embT16 + (size_t)s2 * ET_) : hd;
      } else {
        s_aX[b] = hd;
        s_aC[b] = (pv >= 0) ? (p.CdHist + ((size_t)pv * B_ + b) * D_) : p.dyn_init_c;
        s_dynw[b] = st ? 0 : 1;
      }
    }
    __syncthreads();

    // gather A-frags from global + 32 MFMAs (wave handles batches wave*16..+15)
    const int b = (wave << 4) + (lane & 15);
    const f16* pN = s_aN[b];
    const f16* pX = s_aX[b];
    const f16* pH = p.Hhist + ((size_t)t * B_ + b) * H_;
    f32x4 acc = {0.f, 0.f, 0.f, 0.f};
    if (!isDyn) {
#pragma unroll
      for (int s = 0; s < 32; ++s) {
        const f16* src = (s < 8)  ? (pN + s * 32 + ko)
                       : (s < 16) ? (pX + (s - 8) * 32 + ko)
                                  : (pH + (s - 16) * 32 + ko);
        f16x8 a = *(const f16x8*)src;
        acc = __builtin_amdgcn_mfma_f32_16x16x32_f16(a, w[s], acc, 0, 0, 0);
      }
    } else {
#pragma unroll
      for (int s = 0; s < 32; ++s) {
        const f16* src = (s < 8)  ? (pN + s * 32 + ko)
                       : (s < 24) ? (pH + (s - 8) * 32 + ko)
                                  : (pX + (s - 24) * 32 + ko);
        f16x8 a = *(const f16x8*)src;
        acc = __builtin_amdgcn_mfma_f32_16x16x32_f16(a, w[s], acc, 0, 0, 0);
      }
    }
    // D[m][n]: m = (lane>>4)*4 + j (batch within tile), n = lane&15 (gate row)
#pragma unroll
    for (int j = 0; j < 4; ++j)
      s_scr[(wave << 4) + ((lane >> 4) << 2) + j][lane & 15] = acc[j];
    __syncthreads();

    // epilogue: thread -> (batch, unit)
    {
      const int eb = tid >> 2, un = tid & 3;
      float gi = s_scr[eb][un]      + s_bias[un];
      float gf = s_scr[eb][4 + un]  + s_bias[4 + un];
      float gg = s_scr[eb][8 + un]  + s_bias[8 + un];
      float go = s_scr[eb][12 + un] + s_bias[12 + un];
      float si = sigm(gi), sf = sigm(gf), so = sigm(go);
      float tg = tanh_fast(gg);
      if (!isDyn) {
        float c = sf * s_c[eb][un] + si * tg;
        s_c[eb][un] = c;
        float h = so * tanh_fast(c);
        p.out[((size_t)eb * T_ + t) * H_ + u0 + un] = h;
        p.Hhist[((size_t)(t + 1) * B_ + eb) * H_ + u0 + un] = (f16)h;
      } else {
        float cold = s_aC[eb][u0 + un];
        float c = sf * cold + si * tg;
        float h = so * tanh_fast(c);
        if (s_dynw[eb]) {
          p.CdHist[((size_t)t * B_ + eb) * D_ + u0 + un] = c;
          p.HdHist[((size_t)t * B_ + eb) * D_ + u0 + un] = (f16)h;
        }
      }
    }
    grid_barrier(p.cnt, target);
    target += NBLK_;
  }
}

extern "C" void kernel_launch(void* const* d_in, const int* in_sizes, int n_in,
                              void* d_out, int out_size, void* d_ws, size_t ws_size,
                              hipStream_t stream) {
  (void)in_sizes; (void)n_in; (void)out_size;
  const int* n_input   = (const int*)d_in[0];
  const int* t_input   = (const int*)d_in[1];
  const int* s2d       = (const int*)d_in[3];
  const float* embN    = (const float*)d_in[5];
  const float* embT    = (const float*)d_in[6];
  const float* W_ih    = (const float*)d_in[7];
  const float* W_hh    = (const float*)d_in[8];
  const float* b_ih    = (const float*)d_in[9];
  const float* b_hh    = (const float*)d_in[10];
  const float* Wd_ih   = (const float*)d_in[11];
  const float* Wd_hh   = (const float*)d_in[12];
  const float* bd_ih   = (const float*)d_in[13];
  const float* bd_hh   = (const float*)d_in[14];
  const float* hid_init  = (const float*)d_in[15];
  const float* cell_init = (const float*)d_in[16];
  const float* dyn_init_h = (const float*)d_in[17];
  const float* dyn_init_c = (const float*)d_in[18];

  char* ws = (char*)d_ws;
  unsigned* cnt  = (unsigned*)(ws + OFF_CNT);
  f16* embN16    = (f16*)(ws + OFF_EMBN);
  f16* embT16    = (f16*)(ws + OFF_EMBT);
  f16* dynih16   = (f16*)(ws + OFF_DINH);
  int* prev      = (int*)(ws + OFF_PREV);
  f16* Hhist     = (f16*)(ws + OFF_HH);
  f16* HdHist    = (f16*)(ws + OFF_HD);
  float* CdHist  = (float*)(ws + OFF_CD);
  if (ws_size < WS_NEED) return;   // would corrupt memory otherwise; fail cleanly

  setup_kernel<<<dim3((VN_ * EN_ + NTHR_ - 1) / NTHR_), dim3(NTHR_), 0, stream>>>(
      embN, embT, hid_init, dyn_init_h, embN16, embT16, dynih16, Hhist, cnt);
  prev_kernel<<<dim3((B_ * T_ + NTHR_ - 1) / NTHR_), dim3(NTHR_), 0, stream>>>(
      t_input, s2d, prev);

  RnnParams prm;
  prm.n_input = n_input; prm.t_input = t_input; prm.s2d = s2d;
  prm.W_ih = W_ih; prm.W_hh = W_hh; prm.b_ih = b_ih; prm.b_hh = b_hh;
  prm.Wd_ih = Wd_ih; prm.Wd_hh = Wd_hh; prm.bd_ih = bd_ih; prm.bd_hh = bd_hh;
  prm.cell_init = cell_init; prm.dyn_init_c = dyn_init_c;
  prm.embN16 = embN16; prm.embT16 = embT16; prm.dynih16 = dynih16;
  prm.prev = prev; prm.Hhist = Hhist; prm.HdHist = HdHist; prm.CdHist = CdHist;
  prm.out = (float*)d_out; prm.cnt = cnt;

  void* args[] = { &prm };
  hipError_t e = hipLaunchCooperativeKernel((const void*)rnn_main,
                                            dim3(NBLK_), dim3(NTHR_), args, 0, stream);
  if (e != hipSuccess) {
    // co-residency is still near-certain at 192 blocks / 256 CUs, 1 block/CU
    rnn_main<<<dim3(NBLK_), dim3(NTHR_), 0, stream>>>(prm);
  }
}

// Round 2
// 2537.386 us; speedup vs baseline: 2.5553x; 2.5553x over previous
//
#include <hip/hip_runtime.h>

// DynamicRNNEncoder on MI355X — round 2.
// Persistent cooperative kernel; weights register-resident (f16).
// Cross-block state via fine-grained coherent (sc0/sc1) accesses; relaxed
// sharded grid barrier (no buffer_wbl2 / buffer_inv on the critical path).

typedef _Float16 f16;
typedef _Float16 f16x8 __attribute__((ext_vector_type(8)));
typedef float f32x4 __attribute__((ext_vector_type(4)));

#define B_ 64
#define T_ 256
#define H_ 512
#define EN_ 256
#define ET_ 256
#define D_ 256
#define VN_ 300
#define VS_ 100

#define NB_MAIN_ 128   // 4 main units (16 gate rows) each
#define NB_DYN_ 64     // 4 dyn units each
#define NBLK_ 192
#define NTHR_ 256
#define NSH_ 16        // barrier counter shards (64B apart)
#define PER_SHARD_ (NBLK_ / NSH_)   // 12

// ---- workspace layout (bytes, all 1024-aligned) ----
static constexpr size_t OFF_CNT  = 0;                                   // 16 shard counters (+pad)
static constexpr size_t OFF_EMBN = 1024;                                // embN f16  [300][256]
static constexpr size_t OFF_EMBT = OFF_EMBN + (size_t)VN_ * EN_ * 2;    // embT f16  [100][256]
static constexpr size_t OFF_DINH = OFF_EMBT + (size_t)VS_ * ET_ * 2;    // dyn_init_h f16 [256]
static constexpr size_t OFF_PREV = OFF_DINH + 1024;                     // prev int32 [T][B]
static constexpr size_t OFF_HH   = OFF_PREV + (size_t)T_ * B_ * 4;      // Hhist f16 [T+1][B][H]
static constexpr size_t OFF_HD   = OFF_HH + (size_t)(T_ + 1) * B_ * H_ * 2; // HdHist f16 [T][B][D]
static constexpr size_t OFF_CD   = OFF_HD + (size_t)T_ * B_ * D_ * 2;   // CdHist f32 [T][B][D]
static constexpr size_t WS_NEED  = OFF_CD + (size_t)T_ * B_ * D_ * 4;   // ~42.3 MB

struct RnnParams {
  const int* n_input; const int* t_input; const int* s2d;
  const float* W_ih; const float* W_hh; const float* b_ih; const float* b_hh;
  const float* Wd_ih; const float* Wd_hh; const float* bd_ih; const float* bd_hh;
  const float* cell_init; const float* dyn_init_c;
  const f16* embN16; const f16* embT16; const f16* dynih16;
  const int* prev;
  f16* Hhist; f16* HdHist; float* CdHist;
  float* out; unsigned* cnt;
};

__device__ __forceinline__ float sigm(float x) { return 1.f / (1.f + __expf(-x)); }
__device__ __forceinline__ float tanh_fast(float x) {
  float e = __expf(2.f * x);
  return 1.f - 2.f / (e + 1.f);
}

// ---- fine-grained coherent (bypass non-coherent L1/L2) helpers ----
__device__ __forceinline__ unsigned long long cload8(const void* p) {
  return __hip_atomic_load((const unsigned long long*)p, __ATOMIC_RELAXED,
                           __HIP_MEMORY_SCOPE_AGENT);
}
__device__ __forceinline__ void cstore8(void* p, unsigned long long v) {
  __hip_atomic_store((unsigned long long*)p, v, __ATOMIC_RELAXED,
                     __HIP_MEMORY_SCOPE_AGENT);
}
__device__ __forceinline__ f16x8 cload16(const f16* p) {
  union { unsigned long long u[2]; f16x8 v; } r;
  r.u[0] = cload8(p);
  r.u[1] = cload8(p + 4);
  return r.v;
}

// Relaxed sharded grid barrier. Ordering: __syncthreads drains vmcnt(0) for
// every thread's (sc0sc1) stores before the shard add is issued; consumers'
// coherent loads after the barrier read the coherent point directly.
__device__ __forceinline__ void grid_barrier(unsigned* cnt, unsigned tgt, int bid) {
  __syncthreads();
  if (threadIdx.x == 0)
    __hip_atomic_fetch_add(&cnt[(bid & (NSH_ - 1)) << 4], 1u,
                           __ATOMIC_RELAXED, __HIP_MEMORY_SCOPE_AGENT);
  if (threadIdx.x < NSH_) {
    while (__hip_atomic_load(&cnt[threadIdx.x << 4], __ATOMIC_RELAXED,
                             __HIP_MEMORY_SCOPE_AGENT) < tgt)
      __builtin_amdgcn_s_sleep(2);
  }
  __syncthreads();
}

// ---- setup: f16 conversions, Hhist[0] init, barrier counters reset ----
__global__ void setup_kernel(const float* embN, const float* embT,
                             const float* hid_init, const float* dyn_init_h,
                             f16* embN16, f16* embT16, f16* dynih16,
                             f16* Hhist0, unsigned* cnt) {
  int i = blockIdx.x * blockDim.x + threadIdx.x;
  if (i < 256)       cnt[i] = 0u;
  if (i < VN_ * EN_) embN16[i] = (f16)embN[i];
  if (i < VS_ * ET_) embT16[i] = (f16)embT[i];
  if (i < D_)        dynih16[i] = (f16)dyn_init_h[i];
  if (i < B_ * H_)   Hhist0[i] = (f16)hid_init[i & (H_ - 1)];
}

// ---- prev-occurrence table: prev[t][b] = last t'<t with same (dynamic) token ----
__global__ void prev_kernel(const int* t_input, const int* s2d, int* prev) {
  int idx = blockIdx.x * blockDim.x + threadIdx.x;
  if (idx >= B_ * T_) return;
  int b = idx / T_, t = idx % T_;
  int tt = t_input[b * T_ + t];
  int p = -1;
  if (s2d[tt] != tt) {
    for (int q = t - 1; q >= 0; --q)
      if (t_input[b * T_ + q] == tt) { p = q; break; }
  }
  prev[t * B_ + b] = p;
}

__device__ __forceinline__ void resolve(const RnnParams& p, bool isDyn, int t, int b,
                                        const f16** aN, const f16** aX,
                                        const float** aC, int* dynw) {
  const int nt = p.n_input[b * T_ + t];
  aN[b] = p.embN16 + (size_t)nt * EN_;
  const int tt = p.t_input[b * T_ + t];
  const int pv = p.prev[t * B_ + b];
  const f16* hd = (pv >= 0) ? (p.HdHist + ((size_t)pv * B_ + b) * D_) : p.dynih16;
  const int s2 = p.s2d[tt];
  const bool st = (s2 == tt);
  if (!isDyn) {
    aX[b] = st ? (p.embT16 + (size_t)s2 * ET_) : hd;
  } else {
    aX[b] = hd;
    aC[b] = (pv >= 0) ? (p.CdHist + ((size_t)pv * B_ + b) * D_) : p.dyn_init_c;
    dynw[b] = st ? 0 : 1;
  }
}

// ---- main cooperative recurrent kernel ----
__global__ __launch_bounds__(NTHR_, 1) void rnn_main(RnnParams p) {
  const int blk  = blockIdx.x;
  const int tid  = threadIdx.x;
  const int wave = tid >> 6;
  const int lane = tid & 63;
  const bool isDyn = (blk >= NB_MAIN_);
  const int u0 = isDyn ? (blk - NB_MAIN_) * 4 : blk * 4;

  __shared__ float s_bias[16];
  __shared__ float s_scr[64][17];
  __shared__ const f16*  s_aN[2][64];
  __shared__ const f16*  s_aX[2][64];
  __shared__ const float* s_aC[2][64];
  __shared__ int s_dynw[2][64];

  // ---- one-time: weights into registers ----
  // lane l supplies B-frag elems: B[k = s*32 + (l>>4)*8 + j][n = l&15]
  const int nIdx = lane & 15;
  const int ui = nIdx & 3, gate = nIdx >> 2;
  const int ko = (lane >> 4) * 8;
  f16x8 w[32];
  if (!isDyn) {
    const int r = gate * H_ + u0 + ui;
#pragma unroll
    for (int s = 0; s < 32; ++s) {
      const int k = s * 32 + ko;           // [0,256)=embN [256,512)=h_tensor [512,1024)=h
      const float* src = (k < 512) ? (p.W_ih + (size_t)r * 512 + k)
                                   : (p.W_hh + (size_t)r * 512 + (k - 512));
      f16x8 v;
#pragma unroll
      for (int j = 0; j < 8; ++j) v[j] = (f16)src[j];
      w[s] = v;
    }
  } else {
    const int r = gate * D_ + u0 + ui;
#pragma unroll
    for (int s = 0; s < 32; ++s) {
      const int k = s * 32 + ko;           // [0,256)=embN [256,768)=h [768,1024)=hd_prev
      const float* src = (k < 768) ? (p.Wd_ih + (size_t)r * 768 + k)
                                   : (p.Wd_hh + (size_t)r * 256 + (k - 768));
      f16x8 v;
#pragma unroll
      for (int j = 0; j < 8; ++j) v[j] = (f16)src[j];
      w[s] = v;
    }
  }
  if (tid < 16) {
    int g2 = tid >> 2, un2 = tid & 3;
    s_bias[tid] = isDyn ? (p.bd_ih[g2 * D_ + u0 + un2] + p.bd_hh[g2 * D_ + u0 + un2])
                        : (p.b_ih[g2 * H_ + u0 + un2] + p.b_hh[g2 * H_ + u0 + un2]);
  }
  // main cell state lives in epilogue-thread registers
  float creg[4] = {0.f, 0.f, 0.f, 0.f};
  if (tid < 64 && !isDyn) {
#pragma unroll
    for (int un = 0; un < 4; ++un) creg[un] = p.cell_init[u0 + un];
  }
  // pointers for t = 0
  if (tid < 64)
    resolve(p, isDyn, 0, tid, s_aN[0], s_aX[0], s_aC[0], s_dynw[0]);
  __syncthreads();

  for (int t = 0; t < T_; ++t) {
    const int pb = t & 1;
    // ---- gather A-frags + 32 MFMAs (wave handles batches wave*16..+15) ----
    const int b = (wave << 4) + (lane & 15);
    const f16* pN = s_aN[pb][b];
    const f16* pX = s_aX[pb][b];
    const f16* pH = p.Hhist + ((size_t)t * B_ + b) * H_;
    f32x4 ac[4] = {{0,0,0,0},{0,0,0,0},{0,0,0,0},{0,0,0,0}};
    if (!isDyn) {
#pragma unroll
      for (int s = 0; s < 32; ++s) {
        f16x8 a;
        if (s < 8)       a = *(const f16x8*)(pN + s * 32 + ko);
        else if (s < 16) a = cload16(pX + (s - 8) * 32 + ko);
        else             a = cload16(pH + (s - 16) * 32 + ko);
        ac[s & 3] = __builtin_amdgcn_mfma_f32_16x16x32_f16(a, w[s], ac[s & 3], 0, 0, 0);
      }
    } else {
#pragma unroll
      for (int s = 0; s < 32; ++s) {
        f16x8 a;
        if (s < 8)       a = *(const f16x8*)(pN + s * 32 + ko);
        else if (s < 24) a = cload16(pH + (s - 8) * 32 + ko);
        else             a = cload16(pX + (s - 24) * 32 + ko);
        ac[s & 3] = __builtin_amdgcn_mfma_f32_16x16x32_f16(a, w[s], ac[s & 3], 0, 0, 0);
      }
    }
    f32x4 acc = (ac[0] + ac[1]) + (ac[2] + ac[3]);
    // D[m][n]: m = (lane>>4)*4 + j (batch in tile), n = lane&15 (gate row)
#pragma unroll
    for (int j = 0; j < 4; ++j)
      s_scr[(wave << 4) + ((lane >> 4) << 2) + j][lane & 15] = acc[j];
    __syncthreads();

    if (tid < 64) {
      // ---- epilogue: one batch per thread, 4 units ----
      const int eb = tid;
      float g[16];
#pragma unroll
      for (int n = 0; n < 16; ++n) g[n] = s_scr[eb][n] + s_bias[n];
      if (!isDyn) {
        float4 ho;
        union { f16 h[4]; unsigned long long u; } pk;
#pragma unroll
        for (int un = 0; un < 4; ++un) {
          float c = sigm(g[4 + un]) * creg[un] + sigm(g[un]) * tanh_fast(g[8 + un]);
          creg[un] = c;
          float h = sigm(g[12 + un]) * tanh_fast(c);
          (&ho.x)[un] = h;
          pk.h[un] = (f16)h;
        }
        *(float4*)&p.out[((size_t)eb * T_ + t) * H_ + u0] = ho;
        cstore8(&p.Hhist[((size_t)(t + 1) * B_ + eb) * H_ + u0], pk.u);
      } else {
        const float* cp = s_aC[pb][eb] + u0;
        union { unsigned long long u; float f[2]; } ua, ub, oa, ob;
        ua.u = cload8(cp); ub.u = cload8(cp + 2);
        float cold[4] = {ua.f[0], ua.f[1], ub.f[0], ub.f[1]};
        union { f16 h[4]; unsigned long long u; } pk;
#pragma unroll
        for (int un = 0; un < 4; ++un) {
          float c = sigm(g[4 + un]) * cold[un] + sigm(g[un]) * tanh_fast(g[8 + un]);
          float h = sigm(g[12 + un]) * tanh_fast(c);
          pk.h[un] = (f16)h;
          if (un < 2) oa.f[un] = c; else ob.f[un - 2] = c;
        }
        if (s_dynw[pb][eb]) {
          cstore8(&p.HdHist[((size_t)t * B_ + eb) * D_ + u0], pk.u);
          float* cd = &p.CdHist[((size_t)t * B_ + eb) * D_ + u0];
          cstore8(cd, oa.u);
          cstore8(cd + 2, ob.u);
        }
      }
    } else if (tid < 128 && t + 1 < T_) {
      // ---- wave 1: resolve next step's pointers concurrently ----
      resolve(p, isDyn, t + 1, tid - 64,
              s_aN[pb ^ 1], s_aX[pb ^ 1], s_aC[pb ^ 1], s_dynw[pb ^ 1]);
    }
    grid_barrier(p.cnt, (unsigned)(t + 1) * PER_SHARD_, blk);
  }
}

extern "C" void kernel_launch(void* const* d_in, const int* in_sizes, int n_in,
                              void* d_out, int out_size, void* d_ws, size_t ws_size,
                              hipStream_t stream) {
  (void)in_sizes; (void)n_in; (void)out_size;
  const int* n_input   = (const int*)d_in[0];
  const int* t_input   = (const int*)d_in[1];
  const int* s2d       = (const int*)d_in[3];
  const float* embN    = (const float*)d_in[5];
  const float* embT    = (const float*)d_in[6];
  const float* W_ih    = (const float*)d_in[7];
  const float* W_hh    = (const float*)d_in[8];
  const float* b_ih    = (const float*)d_in[9];
  const float* b_hh    = (const float*)d_in[10];
  const float* Wd_ih   = (const float*)d_in[11];
  const float* Wd_hh   = (const float*)d_in[12];
  const float* bd_ih   = (const float*)d_in[13];
  const float* bd_hh   = (const float*)d_in[14];
  const float* hid_init  = (const float*)d_in[15];
  const float* cell_init = (const float*)d_in[16];
  const float* dyn_init_h = (const float*)d_in[17];
  const float* dyn_init_c = (const float*)d_in[18];

  char* ws = (char*)d_ws;
  unsigned* cnt  = (unsigned*)(ws + OFF_CNT);
  f16* embN16    = (f16*)(ws + OFF_EMBN);
  f16* embT16    = (f16*)(ws + OFF_EMBT);
  f16* dynih16   = (f16*)(ws + OFF_DINH);
  int* prev      = (int*)(ws + OFF_PREV);
  f16* Hhist     = (f16*)(ws + OFF_HH);
  f16* HdHist    = (f16*)(ws + OFF_HD);
  float* CdHist  = (float*)(ws + OFF_CD);
  if (ws_size < WS_NEED) return;

  setup_kernel<<<dim3((VN_ * EN_ + NTHR_ - 1) / NTHR_), dim3(NTHR_), 0, stream>>>(
      embN, embT, hid_init, dyn_init_h, embN16, embT16, dynih16, Hhist, cnt);
  prev_kernel<<<dim3((B_ * T_ + NTHR_ - 1) / NTHR_), dim3(NTHR_), 0, stream>>>(
      t_input, s2d, prev);

  RnnParams prm;
  prm.n_input = n_input; prm.t_input = t_input; prm.s2d = s2d;
  prm.W_ih = W_ih; prm.W_hh = W_hh; prm.b_ih = b_ih; prm.b_hh = b_hh;
  prm.Wd_ih = Wd_ih; prm.Wd_hh = Wd_hh; prm.bd_ih = bd_ih; prm.bd_hh = bd_hh;
  prm.cell_init = cell_init; prm.dyn_init_c = dyn_init_c;
  prm.embN16 = embN16; prm.embT16 = embT16; prm.dynih16 = dynih16;
  prm.prev = prev; prm.Hhist = Hhist; prm.HdHist = HdHist; prm.CdHist = CdHist;
  prm.out = (float*)d_out; prm.cnt = cnt;

  void* args[] = { &prm };
  hipError_t e = hipLaunchCooperativeKernel((const void*)rnn_main,
                                            dim3(NBLK_), dim3(NTHR_), args, 0, stream);
  if (e != hipSuccess) {
    rnn_main<<<dim3(NBLK_), dim3(NTHR_), 0, stream>>>(prm);
  }
}

// Round 3
// 2026.824 us; speedup vs baseline: 3.1990x; 1.2519x over previous
//
#include <hip/hip_runtime.h>

// DynamicRNNEncoder on MI355X — round 3.
// Persistent cooperative kernel; weights register-resident (f16).
// Cross-block state: CACHED vector loads (fresh-address-per-step + entry fence
// makes them coherent), sc0sc1 write-through stores, relaxed sharded barrier.

typedef _Float16 f16;
typedef _Float16 f16x8 __attribute__((ext_vector_type(8)));
typedef float f32x4 __attribute__((ext_vector_type(4)));

#define B_ 64
#define T_ 256
#define H_ 512
#define EN_ 256
#define ET_ 256
#define D_ 256
#define VN_ 300
#define VS_ 100

#define NB_MAIN_ 128   // 4 main units (16 gate rows) each
#define NB_DYN_ 64     // 4 dyn units each
#define NBLK_ 192
#define NTHR_ 256
#define NSH_ 16        // barrier counter shards (64B apart)
#define PER_SHARD_ (NBLK_ / NSH_)   // 12

// ---- workspace layout (bytes, all 1024-aligned) ----
static constexpr size_t OFF_CNT  = 0;                                   // 16 shard counters (+pad)
static constexpr size_t OFF_EMBN = 1024;                                // embN f16  [300][256]
static constexpr size_t OFF_EMBT = OFF_EMBN + (size_t)VN_ * EN_ * 2;    // embT f16  [100][256]
static constexpr size_t OFF_DINH = OFF_EMBT + (size_t)VS_ * ET_ * 2;    // dyn_init_h f16 [256]
static constexpr size_t OFF_PREV = OFF_DINH + 1024;                     // prev int32 [T][B]
static constexpr size_t OFF_HH   = OFF_PREV + (size_t)T_ * B_ * 4;      // Hhist f16 [T+1][B][H]
static constexpr size_t OFF_HD   = OFF_HH + (size_t)(T_ + 1) * B_ * H_ * 2; // HdHist f16 [T][B][D]
static constexpr size_t OFF_CD   = OFF_HD + (size_t)T_ * B_ * D_ * 2;   // CdHist f32 [T][B][D]
static constexpr size_t WS_NEED  = OFF_CD + (size_t)T_ * B_ * D_ * 4;   // ~42.3 MB

struct RnnParams {
  const int* n_input; const int* t_input; const int* s2d;
  const float* W_ih; const float* W_hh; const float* b_ih; const float* b_hh;
  const float* Wd_ih; const float* Wd_hh; const float* bd_ih; const float* bd_hh;
  const float* cell_init; const float* dyn_init_c;
  const f16* embN16; const f16* embT16; const f16* dynih16;
  const int* prev;
  f16* Hhist; f16* HdHist; float* CdHist;
  float* out; unsigned* cnt;
};

__device__ __forceinline__ float sigm(float x) { return 1.f / (1.f + __expf(-x)); }
__device__ __forceinline__ float tanh_fast(float x) {
  float e = __expf(2.f * x);
  return 1.f - 2.f / (e + 1.f);
}

// ---- coherent-point store helpers (sc0sc1 write-through) ----
__device__ __forceinline__ void cstore8(void* p, unsigned long long v) {
  __hip_atomic_store((unsigned long long*)p, v, __ATOMIC_RELAXED,
                     __HIP_MEMORY_SCOPE_AGENT);
}

// Relaxed sharded grid barrier. Ordering: __syncthreads drains vmcnt(0) for
// every thread's (sc0sc1) stores before the shard add is issued.
__device__ __forceinline__ void grid_barrier(unsigned* cnt, unsigned tgt, int bid) {
  __syncthreads();
  if (threadIdx.x == 0)
    __hip_atomic_fetch_add(&cnt[(bid & (NSH_ - 1)) << 4], 1u,
                           __ATOMIC_RELAXED, __HIP_MEMORY_SCOPE_AGENT);
  if (threadIdx.x < NSH_) {
    while (__hip_atomic_load(&cnt[threadIdx.x << 4], __ATOMIC_RELAXED,
                             __HIP_MEMORY_SCOPE_AGENT) < tgt)
      __builtin_amdgcn_s_sleep(2);
  }
  __syncthreads();
}

// ---- setup: f16 conversions, Hhist[0] init, barrier counters reset ----
__global__ void setup_kernel(const float* embN, const float* embT,
                             const float* hid_init, const float* dyn_init_h,
                             f16* embN16, f16* embT16, f16* dynih16,
                             f16* Hhist0, unsigned* cnt) {
  int i = blockIdx.x * blockDim.x + threadIdx.x;
  if (i < 256)       cnt[i] = 0u;
  if (i < VN_ * EN_) embN16[i] = (f16)embN[i];
  if (i < VS_ * ET_) embT16[i] = (f16)embT[i];
  if (i < D_)        dynih16[i] = (f16)dyn_init_h[i];
  if (i < B_ * H_)   Hhist0[i] = (f16)hid_init[i & (H_ - 1)];
  __threadfence();   // flush to coherent point (rnn_main starts with inv'd caches)
}

// ---- prev-occurrence table: prev[t][b] = last t'<t with same (dynamic) token ----
__global__ void prev_kernel(const int* t_input, const int* s2d, int* prev) {
  int idx = blockIdx.x * blockDim.x + threadIdx.x;
  if (idx < B_ * T_) {
    int b = idx / T_, t = idx % T_;
    int tt = t_input[b * T_ + t];
    int p = -1;
    if (s2d[tt] != tt) {
      for (int q = t - 1; q >= 0; --q)
        if (t_input[b * T_ + q] == tt) { p = q; break; }
    }
    prev[t * B_ + b] = p;
  }
  __threadfence();
}

__device__ __forceinline__ void resolve(const RnnParams& p, bool isDyn, int t, int b,
                                        const f16** aN, const f16** aX,
                                        const float** aC, int* dynw) {
  const int nt = p.n_input[b * T_ + t];
  aN[b] = p.embN16 + (size_t)nt * EN_;
  const int tt = p.t_input[b * T_ + t];
  const int pv = p.prev[t * B_ + b];
  const f16* hd = (pv >= 0) ? (p.HdHist + ((size_t)pv * B_ + b) * D_) : p.dynih16;
  const int s2 = p.s2d[tt];
  const bool st = (s2 == tt);
  if (!isDyn) {
    aX[b] = st ? (p.embT16 + (size_t)s2 * ET_) : hd;
  } else {
    aX[b] = hd;
    aC[b] = (pv >= 0) ? (p.CdHist + ((size_t)pv * B_ + b) * D_) : p.dyn_init_c;
    dynw[b] = st ? 0 : 1;
  }
}

// ---- main cooperative recurrent kernel ----
__global__ __launch_bounds__(NTHR_, 1) void rnn_main(RnnParams p) {
  const int blk  = blockIdx.x;
  const int tid  = threadIdx.x;
  const int wave = tid >> 6;
  const int lane = tid & 63;
  const bool isDyn = (blk >= NB_MAIN_);
  const int u0 = isDyn ? (blk - NB_MAIN_) * 4 : blk * 4;

  // Entry fence: invalidate L1/L2 so every cached read this launch re-fetches
  // from the coherent point. All cross-step buffers use fresh addresses per
  // step, so no stale line can be re-cached within the launch.
  __threadfence();

  __shared__ float s_bias[16];
  __shared__ float s_scr[64][17];
  __shared__ const f16*  s_aN[2][64];
  __shared__ const f16*  s_aX[2][64];
  __shared__ const float* s_aC[2][64];
  __shared__ int s_dynw[2][64];

  // ---- one-time: weights into registers ----
  // lane l supplies B-frag elems: B[k = s*32 + (l>>4)*8 + j][n = l&15]
  const int nIdx = lane & 15;
  const int ui = nIdx & 3, gate = nIdx >> 2;
  const int ko = (lane >> 4) * 8;
  f16x8 w[32];
  if (!isDyn) {
    const int r = gate * H_ + u0 + ui;
#pragma unroll
    for (int s = 0; s < 32; ++s) {
      const int k = s * 32 + ko;           // [0,256)=embN [256,512)=h_tensor [512,1024)=h
      const float* src = (k < 512) ? (p.W_ih + (size_t)r * 512 + k)
                                   : (p.W_hh + (size_t)r * 512 + (k - 512));
      f16x8 v;
#pragma unroll
      for (int j = 0; j < 8; ++j) v[j] = (f16)src[j];
      w[s] = v;
    }
  } else {
    const int r = gate * D_ + u0 + ui;
#pragma unroll
    for (int s = 0; s < 32; ++s) {
      const int k = s * 32 + ko;           // [0,256)=embN [256,768)=h [768,1024)=hd_prev
      const float* src = (k < 768) ? (p.Wd_ih + (size_t)r * 768 + k)
                                   : (p.Wd_hh + (size_t)r * 256 + (k - 768));
      f16x8 v;
#pragma unroll
      for (int j = 0; j < 8; ++j) v[j] = (f16)src[j];
      w[s] = v;
    }
  }
  if (tid < 16) {
    int g2 = tid >> 2, un2 = tid & 3;
    s_bias[tid] = isDyn ? (p.bd_ih[g2 * D_ + u0 + un2] + p.bd_hh[g2 * D_ + u0 + un2])
                        : (p.b_ih[g2 * H_ + u0 + un2] + p.b_hh[g2 * H_ + u0 + un2]);
  }
  float creg[4] = {0.f, 0.f, 0.f, 0.f};
  if (tid < 64 && !isDyn) {
#pragma unroll
    for (int un = 0; un < 4; ++un) creg[un] = p.cell_init[u0 + un];
  }
  if (tid < 64)
    resolve(p, isDyn, 0, tid, s_aN[0], s_aX[0], s_aC[0], s_dynw[0]);
  __syncthreads();

  for (int t = 0; t < T_; ++t) {
    const int pb = t & 1;
    // ---- gather A-frags (cached vector loads) + 32 MFMAs ----
    const int b = (wave << 4) + (lane & 15);
    const f16* pN = s_aN[pb][b];
    const f16* pX = s_aX[pb][b];
    const f16* pH = p.Hhist + ((size_t)t * B_ + b) * H_;
    f32x4 ac[4] = {{0,0,0,0},{0,0,0,0},{0,0,0,0},{0,0,0,0}};
    if (!isDyn) {
#pragma unroll
      for (int s = 0; s < 32; ++s) {
        f16x8 a;
        if (s < 8)       a = *(const f16x8*)(pN + s * 32 + ko);
        else if (s < 16) a = *(const f16x8*)(pX + (s - 8) * 32 + ko);
        else             a = *(const f16x8*)(pH + (s - 16) * 32 + ko);
        ac[s & 3] = __builtin_amdgcn_mfma_f32_16x16x32_f16(a, w[s], ac[s & 3], 0, 0, 0);
      }
    } else {
#pragma unroll
      for (int s = 0; s < 32; ++s) {
        f16x8 a;
        if (s < 8)       a = *(const f16x8*)(pN + s * 32 + ko);
        else if (s < 24) a = *(const f16x8*)(pH + (s - 8) * 32 + ko);
        else             a = *(const f16x8*)(pX + (s - 24) * 32 + ko);
        ac[s & 3] = __builtin_amdgcn_mfma_f32_16x16x32_f16(a, w[s], ac[s & 3], 0, 0, 0);
      }
    }
    f32x4 acc = (ac[0] + ac[1]) + (ac[2] + ac[3]);
    // D[m][n]: m = (lane>>4)*4 + j (batch in tile), n = lane&15 (gate row)
#pragma unroll
    for (int j = 0; j < 4; ++j)
      s_scr[(wave << 4) + ((lane >> 4) << 2) + j][lane & 15] = acc[j];
    __syncthreads();

    if (tid < 64) {
      // ---- epilogue: one batch per thread, 4 units ----
      const int eb = tid;
      float g[16];
#pragma unroll
      for (int n = 0; n < 16; ++n) g[n] = s_scr[eb][n] + s_bias[n];
      if (!isDyn) {
        float4 ho;
        union { f16 h[4]; unsigned long long u; } pk;
#pragma unroll
        for (int un = 0; un < 4; ++un) {
          float c = sigm(g[4 + un]) * creg[un] + sigm(g[un]) * tanh_fast(g[8 + un]);
          creg[un] = c;
          float h = sigm(g[12 + un]) * tanh_fast(c);
          (&ho.x)[un] = h;
          pk.h[un] = (f16)h;
        }
        *(float4*)&p.out[((size_t)eb * T_ + t) * H_ + u0] = ho;
        cstore8(&p.Hhist[((size_t)(t + 1) * B_ + eb) * H_ + u0], pk.u);
      } else {
        const float4 cv = *(const float4*)(s_aC[pb][eb] + u0);  // cached read
        const float cold[4] = {cv.x, cv.y, cv.z, cv.w};
        union { unsigned long long u; float f[2]; } oa, ob;
        union { f16 h[4]; unsigned long long u; } pk;
#pragma unroll
        for (int un = 0; un < 4; ++un) {
          float c = sigm(g[4 + un]) * cold[un] + sigm(g[un]) * tanh_fast(g[8 + un]);
          float h = sigm(g[12 + un]) * tanh_fast(c);
          pk.h[un] = (f16)h;
          if (un < 2) oa.f[un] = c; else ob.f[un - 2] = c;
        }
        if (s_dynw[pb][eb]) {
          cstore8(&p.HdHist[((size_t)t * B_ + eb) * D_ + u0], pk.u);
          float* cd = &p.CdHist[((size_t)t * B_ + eb) * D_ + u0];
          cstore8(cd, oa.u);
          cstore8(cd + 2, ob.u);
        }
      }
    } else if (tid < 128 && t + 1 < T_) {
      // ---- wave 1: resolve next step's pointers concurrently ----
      resolve(p, isDyn, t + 1, tid - 64,
              s_aN[pb ^ 1], s_aX[pb ^ 1], s_aC[pb ^ 1], s_dynw[pb ^ 1]);
    }
    grid_barrier(p.cnt, (unsigned)(t + 1) * PER_SHARD_, blk);
  }
}

extern "C" void kernel_launch(void* const* d_in, const int* in_sizes, int n_in,
                              void* d_out, int out_size, void* d_ws, size_t ws_size,
                              hipStream_t stream) {
  (void)in_sizes; (void)n_in; (void)out_size;
  const int* n_input   = (const int*)d_in[0];
  const int* t_input   = (const int*)d_in[1];
  const int* s2d       = (const int*)d_in[3];
  const float* embN    = (const float*)d_in[5];
  const float* embT    = (const float*)d_in[6];
  const float* W_ih    = (const float*)d_in[7];
  const float* W_hh    = (const float*)d_in[8];
  const float* b_ih    = (const float*)d_in[9];
  const float* b_hh    = (const float*)d_in[10];
  const float* Wd_ih   = (const float*)d_in[11];
  const float* Wd_hh   = (const float*)d_in[12];
  const float* bd_ih   = (const float*)d_in[13];
  const float* bd_hh   = (const float*)d_in[14];
  const float* hid_init  = (const float*)d_in[15];
  const float* cell_init = (const float*)d_in[16];
  const float* dyn_init_h = (const float*)d_in[17];
  const float* dyn_init_c = (const float*)d_in[18];

  char* ws = (char*)d_ws;
  unsigned* cnt  = (unsigned*)(ws + OFF_CNT);
  f16* embN16    = (f16*)(ws + OFF_EMBN);
  f16* embT16    = (f16*)(ws + OFF_EMBT);
  f16* dynih16   = (f16*)(ws + OFF_DINH);
  int* prev      = (int*)(ws + OFF_PREV);
  f16* Hhist     = (f16*)(ws + OFF_HH);
  f16* HdHist    = (f16*)(ws + OFF_HD);
  float* CdHist  = (float*)(ws + OFF_CD);
  if (ws_size < WS_NEED) return;

  setup_kernel<<<dim3((VN_ * EN_ + NTHR_ - 1) / NTHR_), dim3(NTHR_), 0, stream>>>(
      embN, embT, hid_init, dyn_init_h, embN16, embT16, dynih16, Hhist, cnt);
  prev_kernel<<<dim3((B_ * T_ + NTHR_ - 1) / NTHR_), dim3(NTHR_), 0, stream>>>(
      t_input, s2d, prev);

  RnnParams prm;
  prm.n_input = n_input; prm.t_input = t_input; prm.s2d = s2d;
  prm.W_ih = W_ih; prm.W_hh = W_hh; prm.b_ih = b_ih; prm.b_hh = b_hh;
  prm.Wd_ih = Wd_ih; prm.Wd_hh = Wd_hh; prm.bd_ih = bd_ih; prm.bd_hh = bd_hh;
  prm.cell_init = cell_init; prm.dyn_init_c = dyn_init_c;
  prm.embN16 = embN16; prm.embT16 = embT16; prm.dynih16 = dynih16;
  prm.prev = prev; prm.Hhist = Hhist; prm.HdHist = HdHist; prm.CdHist = CdHist;
  prm.out = (float*)d_out; prm.cnt = cnt;

  void* args[] = { &prm };
  hipError_t e = hipLaunchCooperativeKernel((const void*)rnn_main,
                                            dim3(NBLK_), dim3(NTHR_), args, 0, stream);
  if (e != hipSuccess) {
    rnn_main<<<dim3(NBLK_), dim3(NTHR_), 0, stream>>>(prm);
  }
}

// Round 4
// 1864.762 us; speedup vs baseline: 3.4770x; 1.0869x over previous
//
#include <hip/hip_runtime.h>

// DynamicRNNEncoder on MI355X — round 4.
// Persistent cooperative kernel; weights register-resident (f16).
// Cached A-panel loads (fresh-address-per-step + entry fence), sc0sc1
// write-through stores (16B where possible), 64-shard relaxed barrier,
// cd_prev prefetched at loop top to overlap the IF round trip.

typedef _Float16 f16;
typedef _Float16 f16x8 __attribute__((ext_vector_type(8)));
typedef float f32x4 __attribute__((ext_vector_type(4)));

#define B_ 64
#define T_ 256
#define H_ 512
#define EN_ 256
#define ET_ 256
#define D_ 256
#define VN_ 300
#define VS_ 100

#define NB_MAIN_ 128   // 4 main units (16 gate rows) each
#define NB_DYN_ 64     // 4 dyn units each
#define NBLK_ 192
#define NTHR_ 256
#define NSH_ 64        // barrier counter shards (64B apart)
#define PER_SHARD_ (NBLK_ / NSH_)   // 3

// ---- workspace layout (bytes) ----
static constexpr size_t OFF_CNT  = 0;                                   // 64 shards × 64B = 4KB
static constexpr size_t OFF_EMBN = 4096;                                // embN f16  [300][256]
static constexpr size_t OFF_EMBT = OFF_EMBN + (size_t)VN_ * EN_ * 2;    // embT f16  [100][256]
static constexpr size_t OFF_DINH = OFF_EMBT + (size_t)VS_ * ET_ * 2;    // dyn_init_h f16 [256]
static constexpr size_t OFF_PREV = OFF_DINH + 1024;                     // prev int32 [T][B]
static constexpr size_t OFF_HH   = OFF_PREV + (size_t)T_ * B_ * 4;      // Hhist f16 [T+1][B][H]
static constexpr size_t OFF_HD   = OFF_HH + (size_t)(T_ + 1) * B_ * H_ * 2; // HdHist f16 [T][B][D]
static constexpr size_t OFF_CD   = OFF_HD + (size_t)T_ * B_ * D_ * 2;   // CdHist f32 [T][B][D]
static constexpr size_t WS_NEED  = OFF_CD + (size_t)T_ * B_ * D_ * 4;   // ~42.3 MB

struct RnnParams {
  const int* n_input; const int* t_input; const int* s2d;
  const float* W_ih; const float* W_hh; const float* b_ih; const float* b_hh;
  const float* Wd_ih; const float* Wd_hh; const float* bd_ih; const float* bd_hh;
  const float* cell_init; const float* dyn_init_c;
  const f16* embN16; const f16* embT16; const f16* dynih16;
  const int* prev;
  f16* Hhist; f16* HdHist; float* CdHist;
  float* out; unsigned* cnt;
};

__device__ __forceinline__ float sigm(float x) { return 1.f / (1.f + __expf(-x)); }
__device__ __forceinline__ float tanh_fast(float x) {
  float e = __expf(2.f * x);
  return 1.f - 2.f / (e + 1.f);
}

// ---- coherent-point store helpers (sc0sc1 write-through) ----
__device__ __forceinline__ void cstore8(void* p, unsigned long long v) {
  __hip_atomic_store((unsigned long long*)p, v, __ATOMIC_RELAXED,
                     __HIP_MEMORY_SCOPE_AGENT);
}
__device__ __forceinline__ void cstore16(void* p, f32x4 v) {
  asm volatile("global_store_dwordx4 %0, %1, off sc0 sc1"
               :: "v"(p), "v"(v) : "memory");
}

// Relaxed sharded grid barrier. Ordering: __syncthreads drains vmcnt(0) for
// every thread's (sc0sc1) stores before the shard add is issued.
__device__ __forceinline__ void grid_barrier(unsigned* cnt, unsigned tgt, int bid) {
  __syncthreads();
  if (threadIdx.x == 0)
    __hip_atomic_fetch_add(&cnt[(bid & (NSH_ - 1)) << 4], 1u,
                           __ATOMIC_RELAXED, __HIP_MEMORY_SCOPE_AGENT);
  if (threadIdx.x < NSH_) {
    while (__hip_atomic_load(&cnt[threadIdx.x << 4], __ATOMIC_RELAXED,
                             __HIP_MEMORY_SCOPE_AGENT) < tgt)
      __builtin_amdgcn_s_sleep(1);
  }
  __syncthreads();
}

// ---- setup: f16 conversions, Hhist[0] init, barrier counters reset ----
__global__ void setup_kernel(const float* embN, const float* embT,
                             const float* hid_init, const float* dyn_init_h,
                             f16* embN16, f16* embT16, f16* dynih16,
                             f16* Hhist0, unsigned* cnt) {
  int i = blockIdx.x * blockDim.x + threadIdx.x;
  if (i < 1024)      cnt[i] = 0u;          // full 4KB shard region
  if (i < VN_ * EN_) embN16[i] = (f16)embN[i];
  if (i < VS_ * ET_) embT16[i] = (f16)embT[i];
  if (i < D_)        dynih16[i] = (f16)dyn_init_h[i];
  if (i < B_ * H_)   Hhist0[i] = (f16)hid_init[i & (H_ - 1)];
  __threadfence();   // flush to coherent point (rnn_main starts with inv'd caches)
}

// ---- prev-occurrence table: prev[t][b] = last t'<t with same (dynamic) token ----
__global__ void prev_kernel(const int* t_input, const int* s2d, int* prev) {
  int idx = blockIdx.x * blockDim.x + threadIdx.x;
  if (idx < B_ * T_) {
    int b = idx / T_, t = idx % T_;
    int tt = t_input[b * T_ + t];
    int p = -1;
    if (s2d[tt] != tt) {
      for (int q = t - 1; q >= 0; --q)
        if (t_input[b * T_ + q] == tt) { p = q; break; }
    }
    prev[t * B_ + b] = p;
  }
  __threadfence();
}

__device__ __forceinline__ void resolve(const RnnParams& p, bool isDyn, int t, int b,
                                        const f16** aN, const f16** aX,
                                        const float** aC, int* dynw) {
  const int nt = p.n_input[b * T_ + t];
  aN[b] = p.embN16 + (size_t)nt * EN_;
  const int tt = p.t_input[b * T_ + t];
  const int pv = p.prev[t * B_ + b];
  const f16* hd = (pv >= 0) ? (p.HdHist + ((size_t)pv * B_ + b) * D_) : p.dynih16;
  const int s2 = p.s2d[tt];
  const bool st = (s2 == tt);
  if (!isDyn) {
    aX[b] = st ? (p.embT16 + (size_t)s2 * ET_) : hd;
  } else {
    aX[b] = hd;
    aC[b] = (pv >= 0) ? (p.CdHist + ((size_t)pv * B_ + b) * D_) : p.dyn_init_c;
    dynw[b] = st ? 0 : 1;
  }
}

// ---- main cooperative recurrent kernel ----
__global__ __launch_bounds__(NTHR_, 1) void rnn_main(RnnParams p) {
  const int blk  = blockIdx.x;
  const int tid  = threadIdx.x;
  const int wave = tid >> 6;
  const int lane = tid & 63;
  const bool isDyn = (blk >= NB_MAIN_);
  const int u0 = isDyn ? (blk - NB_MAIN_) * 4 : blk * 4;

  // Entry fence: invalidate L1/L2 once so cached reads this launch re-fetch
  // from the coherent point; cross-step buffers are fresh-address-per-step.
  __threadfence();

  __shared__ float s_bias[16];
  __shared__ float s_scr[64][17];
  __shared__ const f16*  s_aN[2][64];
  __shared__ const f16*  s_aX[2][64];
  __shared__ const float* s_aC[2][64];
  __shared__ int s_dynw[2][64];

  // ---- one-time: weights into registers ----
  // lane l supplies B-frag elems: B[k = s*32 + (l>>4)*8 + j][n = l&15]
  const int nIdx = lane & 15;
  const int ui = nIdx & 3, gate = nIdx >> 2;
  const int ko = (lane >> 4) * 8;
  f16x8 w[32];
  if (!isDyn) {
    const int r = gate * H_ + u0 + ui;
#pragma unroll
    for (int s = 0; s < 32; ++s) {
      const int k = s * 32 + ko;           // [0,256)=embN [256,512)=h_tensor [512,1024)=h
      const float* src = (k < 512) ? (p.W_ih + (size_t)r * 512 + k)
                                   : (p.W_hh + (size_t)r * 512 + (k - 512));
      f16x8 v;
#pragma unroll
      for (int j = 0; j < 8; ++j) v[j] = (f16)src[j];
      w[s] = v;
    }
  } else {
    const int r = gate * D_ + u0 + ui;
#pragma unroll
    for (int s = 0; s < 32; ++s) {
      const int k = s * 32 + ko;           // [0,256)=embN [256,768)=h [768,1024)=hd_prev
      const float* src = (k < 768) ? (p.Wd_ih + (size_t)r * 768 + k)
                                   : (p.Wd_hh + (size_t)r * 256 + (k - 768));
      f16x8 v;
#pragma unroll
      for (int j = 0; j < 8; ++j) v[j] = (f16)src[j];
      w[s] = v;
    }
  }
  if (tid < 16) {
    int g2 = tid >> 2, un2 = tid & 3;
    s_bias[tid] = isDyn ? (p.bd_ih[g2 * D_ + u0 + un2] + p.bd_hh[g2 * D_ + u0 + un2])
                        : (p.b_ih[g2 * H_ + u0 + un2] + p.b_hh[g2 * H_ + u0 + un2]);
  }
  float creg[4] = {0.f, 0.f, 0.f, 0.f};
  if (tid < 64 && !isDyn) {
#pragma unroll
    for (int un = 0; un < 4; ++un) creg[un] = p.cell_init[u0 + un];
  }
  if (tid < 64)
    resolve(p, isDyn, 0, tid, s_aN[0], s_aX[0], s_aC[0], s_dynw[0]);
  __syncthreads();

  for (int t = 0; t < T_; ++t) {
    const int pb = t & 1;

    // ---- prefetch cd_prev FIRST (overlaps with the A-load round trip) ----
    float4 cv;
    if (isDyn && tid < 64)
      cv = *(const float4*)(s_aC[pb][tid] + u0);

    // ---- gather A-frags (cached vector loads) + 32 MFMAs ----
    const int b = (wave << 4) + (lane & 15);
    const f16* pN = s_aN[pb][b];
    const f16* pX = s_aX[pb][b];
    const f16* pH = p.Hhist + ((size_t)t * B_ + b) * H_;
    f32x4 ac[4] = {{0,0,0,0},{0,0,0,0},{0,0,0,0},{0,0,0,0}};
    if (!isDyn) {
#pragma unroll
      for (int s = 0; s < 32; ++s) {
        f16x8 a;
        if (s < 8)       a = *(const f16x8*)(pN + s * 32 + ko);
        else if (s < 16) a = *(const f16x8*)(pX + (s - 8) * 32 + ko);
        else             a = *(const f16x8*)(pH + (s - 16) * 32 + ko);
        ac[s & 3] = __builtin_amdgcn_mfma_f32_16x16x32_f16(a, w[s], ac[s & 3], 0, 0, 0);
      }
    } else {
#pragma unroll
      for (int s = 0; s < 32; ++s) {
        f16x8 a;
        if (s < 8)       a = *(const f16x8*)(pN + s * 32 + ko);
        else if (s < 24) a = *(const f16x8*)(pH + (s - 8) * 32 + ko);
        else             a = *(const f16x8*)(pX + (s - 24) * 32 + ko);
        ac[s & 3] = __builtin_amdgcn_mfma_f32_16x16x32_f16(a, w[s], ac[s & 3], 0, 0, 0);
      }
    }
    f32x4 acc = (ac[0] + ac[1]) + (ac[2] + ac[3]);
    // D[m][n]: m = (lane>>4)*4 + j (batch in tile), n = lane&15 (gate row)
#pragma unroll
    for (int j = 0; j < 4; ++j)
      s_scr[(wave << 4) + ((lane >> 4) << 2) + j][lane & 15] = acc[j];
    __syncthreads();

    if (tid < 64) {
      // ---- epilogue: one batch per thread, 4 units (load-free) ----
      const int eb = tid;
      float g[16];
#pragma unroll
      for (int n = 0; n < 16; ++n) g[n] = s_scr[eb][n] + s_bias[n];
      if (!isDyn) {
        float4 ho;
        union { f16 h[4]; unsigned long long u; } pk;
#pragma unroll
        for (int un = 0; un < 4; ++un) {
          float c = sigm(g[4 + un]) * creg[un] + sigm(g[un]) * tanh_fast(g[8 + un]);
          creg[un] = c;
          float h = sigm(g[12 + un]) * tanh_fast(c);
          (&ho.x)[un] = h;
          pk.h[un] = (f16)h;
        }
        *(float4*)&p.out[((size_t)eb * T_ + t) * H_ + u0] = ho;
        cstore8(&p.Hhist[((size_t)(t + 1) * B_ + eb) * H_ + u0], pk.u);
      } else {
        const float cold[4] = {cv.x, cv.y, cv.z, cv.w};
        f32x4 co;
        union { f16 h[4]; unsigned long long u; } pk;
#pragma unroll
        for (int un = 0; un < 4; ++un) {
          float c = sigm(g[4 + un]) * cold[un] + sigm(g[un]) * tanh_fast(g[8 + un]);
          float h = sigm(g[12 + un]) * tanh_fast(c);
          pk.h[un] = (f16)h;
          co[un] = c;
        }
        if (s_dynw[pb][eb]) {
          cstore8(&p.HdHist[((size_t)t * B_ + eb) * D_ + u0], pk.u);
          cstore16(&p.CdHist[((size_t)t * B_ + eb) * D_ + u0], co);
        }
      }
    } else if (tid < 128 && t + 1 < T_) {
      // ---- wave 1: resolve next step's pointers concurrently ----
      resolve(p, isDyn, t + 1, tid - 64,
              s_aN[pb ^ 1], s_aX[pb ^ 1], s_aC[pb ^ 1], s_dynw[pb ^ 1]);
    }
    grid_barrier(p.cnt, (unsigned)(t + 1) * PER_SHARD_, blk);
  }
}

extern "C" void kernel_launch(void* const* d_in, const int* in_sizes, int n_in,
                              void* d_out, int out_size, void* d_ws, size_t ws_size,
                              hipStream_t stream) {
  (void)in_sizes; (void)n_in; (void)out_size;
  const int* n_input   = (const int*)d_in[0];
  const int* t_input   = (const int*)d_in[1];
  const int* s2d       = (const int*)d_in[3];
  const float* embN    = (const float*)d_in[5];
  const float* embT    = (const float*)d_in[6];
  const float* W_ih    = (const float*)d_in[7];
  const float* W_hh    = (const float*)d_in[8];
  const float* b_ih    = (const float*)d_in[9];
  const float* b_hh    = (const float*)d_in[10];
  const float* Wd_ih   = (const float*)d_in[11];
  const float* Wd_hh   = (const float*)d_in[12];
  const float* bd_ih   = (const float*)d_in[13];
  const float* bd_hh   = (const float*)d_in[14];
  const float* hid_init  = (const float*)d_in[15];
  const float* cell_init = (const float*)d_in[16];
  const float* dyn_init_h = (const float*)d_in[17];
  const float* dyn_init_c = (const float*)d_in[18];

  char* ws = (char*)d_ws;
  unsigned* cnt  = (unsigned*)(ws + OFF_CNT);
  f16* embN16    = (f16*)(ws + OFF_EMBN);
  f16* embT16    = (f16*)(ws + OFF_EMBT);
  f16* dynih16   = (f16*)(ws + OFF_DINH);
  int* prev      = (int*)(ws + OFF_PREV);
  f16* Hhist     = (f16*)(ws + OFF_HH);
  f16* HdHist    = (f16*)(ws + OFF_HD);
  float* CdHist  = (float*)(ws + OFF_CD);
  if (ws_size < WS_NEED) return;

  setup_kernel<<<dim3((VN_ * EN_ + NTHR_ - 1) / NTHR_), dim3(NTHR_), 0, stream>>>(
      embN, embT, hid_init, dyn_init_h, embN16, embT16, dynih16, Hhist, cnt);
  prev_kernel<<<dim3((B_ * T_ + NTHR_ - 1) / NTHR_), dim3(NTHR_), 0, stream>>>(
      t_input, s2d, prev);

  RnnParams prm;
  prm.n_input = n_input; prm.t_input = t_input; prm.s2d = s2d;
  prm.W_ih = W_ih; prm.W_hh = W_hh; prm.b_ih = b_ih; prm.b_hh = b_hh;
  prm.Wd_ih = Wd_ih; prm.Wd_hh = Wd_hh; prm.bd_ih = bd_ih; prm.bd_hh = bd_hh;
  prm.cell_init = cell_init; prm.dyn_init_c = dyn_init_c;
  prm.embN16 = embN16; prm.embT16 = embT16; prm.dynih16 = dynih16;
  prm.prev = prev; prm.Hhist = Hhist; prm.HdHist = HdHist; prm.CdHist = CdHist;
  prm.out = (float*)d_out; prm.cnt = cnt;

  void* args[] = { &prm };
  hipError_t e = hipLaunchCooperativeKernel((const void*)rnn_main,
                                            dim3(NBLK_), dim3(NTHR_), args, 0, stream);
  if (e != hipSuccess) {
    rnn_main<<<dim3(NBLK_), dim3(NTHR_), 0, stream>>>(prm);
  }
}